// Round 3
// baseline (462.985 us; speedup 1.0000x reference)
//
#include <hip/hip_runtime.h>
#include <hip/hip_bf16.h>
#include <stdint.h>

// ---------- types ----------
typedef __bf16 bf16_t;
typedef __attribute__((ext_vector_type(8))) __bf16 bf16x8;   // MFMA A/B frag (4 VGPR)
typedef __attribute__((ext_vector_type(4))) float floatx4;   // 16x16 C frag
typedef __attribute__((ext_vector_type(16))) float f32x16;   // 32x32 C frag

typedef __attribute__((address_space(1))) const unsigned int gu32_t;
typedef __attribute__((address_space(3))) unsigned int lu32_t;

// async global->LDS, 16B per lane; LDS dest = wave-uniform base + lane*16
__device__ __forceinline__ void async16(const void* g, void* l) {
    __builtin_amdgcn_global_load_lds((gu32_t*)g, (lu32_t*)l, 16, 0, 0);
}

__device__ __forceinline__ uint32_t pack2(float lo, float hi) {
    union { bf16_t h[2]; uint32_t u; } cv;
    cv.h[0] = (bf16_t)lo; cv.h[1] = (bf16_t)hi;
    return cv.u;
}

// ---------- fp32 -> bf16 convert ----------
__global__ __launch_bounds__(256) void cvt_f32_bf16(const float* __restrict__ in,
                                                    bf16_t* __restrict__ out) {
    int i = (blockIdx.x * 256 + threadIdx.x) * 8;
    float4 a = *(const float4*)(in + i);
    float4 b = *(const float4*)(in + i + 4);
    bf16x8 v;
    v[0] = (bf16_t)a.x; v[1] = (bf16_t)a.y; v[2] = (bf16_t)a.z; v[3] = (bf16_t)a.w;
    v[4] = (bf16_t)b.x; v[5] = (bf16_t)b.y; v[6] = (bf16_t)b.z; v[7] = (bf16_t)b.w;
    *(bf16x8*)(out + i) = v;
}

// ---------- GEMM: C[m,n] = sum_k A[m,k]*B[n,k] + bias (unchanged from R2) ----
template <bool OUT_F32, bool BIAS_ROW>
__global__ __launch_bounds__(256) void gemm_bt(const bf16_t* __restrict__ A,
                                               const bf16_t* __restrict__ B,
                                               const float* __restrict__ bias,
                                               const float* __restrict__ bias2,
                                               int nsplit,
                                               float* __restrict__ Cf,
                                               bf16_t* __restrict__ Cb,
                                               int M, int N, int K, int ldc) {
    __shared__ bf16_t As[128 * 64];
    __shared__ bf16_t Bs[128 * 64];
    const int tid = threadIdx.x;
    const int wave = tid >> 6, lane = tid & 63;
    const int quad = lane >> 4, l16 = lane & 15;
    const int wm = (wave >> 1) * 64, wn = (wave & 1) * 64;
    const int tm = blockIdx.x * 128, tn = blockIdx.y * 128;

    floatx4 acc[4][4];
#pragma unroll
    for (int i = 0; i < 4; ++i)
#pragma unroll
        for (int j = 0; j < 4; ++j) acc[i][j] = floatx4{0.f, 0.f, 0.f, 0.f};

    const bf16_t* Abase = A + (size_t)tm * K;
    const bf16_t* Bbase = B + (size_t)tn * K;
    const int sw = l16 & 7;

    for (int kk = 0; kk < K; kk += 64) {
#pragma unroll
        for (int it = 0; it < 4; ++it) {
            int chunk = it * 256 + tid;
            int r = chunk >> 3, c = chunk & 7;
            int c2 = c ^ (r & 7);
            async16(Abase + r * K + kk + c2 * 8, As + (it * 256 + wave * 64) * 8);
            async16(Bbase + r * K + kk + c2 * 8, Bs + (it * 256 + wave * 64) * 8);
        }
        __syncthreads();
#pragma unroll
        for (int ks = 0; ks < 2; ++ks) {
            bf16x8 af[4], bf[4];
#pragma unroll
            for (int mt = 0; mt < 4; ++mt)
                af[mt] = *(const bf16x8*)(As + (wm + mt * 16 + l16) * 64 +
                                          ((ks * 4 + quad) ^ sw) * 8);
#pragma unroll
            for (int nt = 0; nt < 4; ++nt)
                bf[nt] = *(const bf16x8*)(Bs + (wn + nt * 16 + l16) * 64 +
                                          ((ks * 4 + quad) ^ sw) * 8);
#pragma unroll
            for (int mt = 0; mt < 4; ++mt)
#pragma unroll
                for (int nt = 0; nt < 4; ++nt)
                    acc[mt][nt] = __builtin_amdgcn_mfma_f32_16x16x32_bf16(af[mt], bf[nt],
                                                                          acc[mt][nt], 0, 0, 0);
        }
        __syncthreads();
    }
#pragma unroll
    for (int mt = 0; mt < 4; ++mt)
#pragma unroll
        for (int nt = 0; nt < 4; ++nt)
#pragma unroll
            for (int r = 0; r < 4; ++r) {
                int row = tm + wm + mt * 16 + quad * 4 + r;
                int col = tn + wn + nt * 16 + l16;
                float bv = BIAS_ROW ? bias[row]
                                    : (col < nsplit ? bias[col] : bias2[col - nsplit]);
                float v = acc[mt][nt][r] + bv;
                if (OUT_F32) Cf[(size_t)row * ldc + col] = v;
                else Cb[(size_t)row * ldc + col] = (bf16_t)v;
            }
}

// ---------- flash attention, 32x32x16 MFMA, 2 waves x 32q ----------
// S^T = K Q^T (C: row=key, col=q=lane&31). P^T B-frags for O^T = V^T P^T are
// built in-register: B-frag step s needs C-regs 8(s&1)+4*hi+{0..3}, half local,
// half from lane^32. O^T C-layout has col=q -> alpha rescale is shuffle-free.
// LDS 32KB (Ks 64x128 + Vts 128x64, XOR-swizzled); ~4 blocks/CU.
__global__ __launch_bounds__(128, 2) void flash_attn(const bf16_t* __restrict__ Qp,
                                                     const bf16_t* __restrict__ Kp,
                                                     const bf16_t* __restrict__ Vt,
                                                     bf16_t* __restrict__ O) {
    __shared__ bf16_t Ks[64 * 128];
    __shared__ bf16_t Vts[128 * 64];
    const int tid = threadIdx.x;
    const int wv = tid >> 6, lane = tid & 63;
    const int hi = lane >> 5, l32 = lane & 31;
    const int LD = 4096, T = 4096, S = 2048, HO = 2048;
    const float SL2E = 0.088388347688f * 1.44269504089f;  // log2(e)/sqrt(128)

    const int qrow0 = blockIdx.z * S + blockIdx.x * 64;
    const int krow0 = blockIdx.z * S;
    const int hoff = blockIdx.y * 128;
    const int sw7 = l32 & 7;

    // Q B-frags: b[j] = Q[q = qrow0+wv*32+l32][hoff + 16ks + 8hi + j]
    bf16x8 qf[8];
    const bf16_t* qptr = Qp + (size_t)(qrow0 + wv * 32 + l32) * LD + hoff + hi * 8;
#pragma unroll
    for (int ks = 0; ks < 8; ++ks) qf[ks] = *(const bf16x8*)(qptr + ks * 16);

    float m_i = -3.0e38f, l_i = 0.f;  // stats for q = l32 (replicated across hi)
    f32x16 Oacc[4];
#pragma unroll
    for (int dt = 0; dt < 4; ++dt)
#pragma unroll
        for (int r = 0; r < 16; ++r) Oacc[dt][r] = 0.f;

    for (int kt = 0; kt < 32; ++kt) {
        int kb = krow0 + kt * 64;
        // stage K tile 64 keys x 128 d (16B chunks, source-swizzled in low3)
#pragma unroll
        for (int it = 0; it < 8; ++it) {
            int chunk = it * 128 + tid;
            int r = chunk >> 4, c = chunk & 15;
            int c2 = c ^ (r & 7);
            async16(Kp + (size_t)(kb + r) * LD + hoff + c2 * 8, Ks + chunk * 8);
        }
        // stage V^T tile 128 d x 64 keys
#pragma unroll
        for (int it = 0; it < 8; ++it) {
            int chunk = it * 128 + tid;
            int r = chunk >> 3, c = chunk & 7;
            int c2 = c ^ (r & 7);
            async16(Vt + (size_t)(hoff + r) * T + kb + c2 * 8, Vts + chunk * 8);
        }
        __syncthreads();

        // S^T = K Q^T : sf[mt] covers keys mt*32..+32 x q 32
        f32x16 sf[2];
#pragma unroll
        for (int mt = 0; mt < 2; ++mt)
#pragma unroll
            for (int r = 0; r < 16; ++r) sf[mt][r] = 0.f;
#pragma unroll
        for (int ks = 0; ks < 8; ++ks) {
#pragma unroll
            for (int mt = 0; mt < 2; ++mt) {
                bf16x8 a = *(const bf16x8*)(Ks + (mt * 32 + l32) * 128 +
                                            ((2 * ks + hi) ^ sw7) * 8);
                sf[mt] = __builtin_amdgcn_mfma_f32_32x32x16_bf16(a, qf[ks], sf[mt], 0, 0, 0);
            }
        }

        // online softmax (log2 domain); lane holds 32 keys of q-row l32
        float mx = -3.0e38f;
#pragma unroll
        for (int mt = 0; mt < 2; ++mt)
#pragma unroll
            for (int r = 0; r < 16; ++r) mx = fmaxf(mx, sf[mt][r]);
        mx = fmaxf(mx, __shfl_xor(mx, 32));
        mx *= SL2E;
        float mnew = fmaxf(m_i, mx);
        float alpha = exp2f(m_i - mnew);
        m_i = mnew;

        float rsum = 0.f;
        uint32_t pk[16];
#pragma unroll
        for (int mt = 0; mt < 2; ++mt)
#pragma unroll
            for (int a4 = 0; a4 < 4; ++a4) {
                float p0 = exp2f(sf[mt][4 * a4 + 0] * SL2E - mnew);
                float p1 = exp2f(sf[mt][4 * a4 + 1] * SL2E - mnew);
                float p2 = exp2f(sf[mt][4 * a4 + 2] * SL2E - mnew);
                float p3 = exp2f(sf[mt][4 * a4 + 3] * SL2E - mnew);
                rsum += (p0 + p1) + (p2 + p3);
                pk[mt * 8 + a4 * 2 + 0] = pack2(p0, p1);
                pk[mt * 8 + a4 * 2 + 1] = pack2(p2, p3);
            }
        rsum += __shfl_xor(rsum, 32);
        l_i = l_i * alpha + rsum;

        // rescale O^T (col = q = l32 -> one alpha per lane, no shuffles)
#pragma unroll
        for (int dt = 0; dt < 4; ++dt)
#pragma unroll
            for (int r = 0; r < 16; ++r) Oacc[dt][r] *= alpha;

        // O^T += V^T P^T : per step s (16 keys), build P^T B-frag
#pragma unroll
        for (int s = 0; s < 4; ++s) {
            int base = (s >> 1) * 8 + (s & 1) * 4;
            uint32_t PA0 = pk[base + 0], PA1 = pk[base + 1];
            uint32_t PB0 = pk[base + 2], PB1 = pk[base + 3];
            uint32_t rA0 = (uint32_t)__shfl_xor((int)PA0, 32);
            uint32_t rA1 = (uint32_t)__shfl_xor((int)PA1, 32);
            uint32_t rB0 = (uint32_t)__shfl_xor((int)PB0, 32);
            uint32_t rB1 = (uint32_t)__shfl_xor((int)PB1, 32);
            union { uint32_t u[4]; bf16x8 v; } w;
            w.u[0] = hi ? rB0 : PA0;
            w.u[1] = hi ? rB1 : PA1;
            w.u[2] = hi ? PB0 : rA0;
            w.u[3] = hi ? PB1 : rA1;
#pragma unroll
            for (int dt = 0; dt < 4; ++dt) {
                bf16x8 a = *(const bf16x8*)(Vts + (dt * 32 + l32) * 64 +
                                            ((2 * s + hi) ^ sw7) * 8);
                Oacc[dt] = __builtin_amdgcn_mfma_f32_32x32x16_bf16(a, w.v, Oacc[dt], 0, 0, 0);
            }
        }
        __syncthreads();  // protect Ks/Vts before next restage
    }

    // epilogue: O^T -> O via LDS transpose (reuse Ks; per-wave half, no barrier
    // needed: each wave reads only what it wrote, compiler inserts lgkmcnt).
    float linv = 1.0f / l_i;
    uint32_t* Os = (uint32_t*)Ks + wv * 2048;  // 32 rows(q) x 64 u32(d-pairs)
#pragma unroll
    for (int dt = 0; dt < 4; ++dt)
#pragma unroll
        for (int a4 = 0; a4 < 4; ++a4) {
            // reg 4*a4+t -> d = 32dt + 8*a4 + t + 4hi
            uint32_t q0 = pack2(Oacc[dt][4 * a4 + 0] * linv, Oacc[dt][4 * a4 + 1] * linv);
            uint32_t q1 = pack2(Oacc[dt][4 * a4 + 2] * linv, Oacc[dt][4 * a4 + 3] * linv);
            int d2 = 16 * dt + 4 * a4 + 2 * hi;  // d/2 for the (t=0,1) pair
            Os[l32 * 64 + ((d2 + 2 * l32) & 63)] = q0;
            Os[l32 * 64 + ((d2 + 1 + 2 * l32) & 63)] = q1;
        }
#pragma unroll
    for (int r = 0; r < 32; ++r) {
        uint32_t v = Os[r * 64 + ((lane + 2 * r) & 63)];
        uint32_t* orow = (uint32_t*)(O + (size_t)(qrow0 + wv * 32 + r) * HO + hoff);
        orow[lane] = v;
    }
}

// ---------- launch ----------
extern "C" void kernel_launch(void* const* d_in, const int* in_sizes, int n_in,
                              void* d_out, int out_size, void* d_ws, size_t ws_size,
                              hipStream_t stream) {
    const float* x  = (const float*)d_in[0];
    const float* Wq = (const float*)d_in[1];
    const float* bq = (const float*)d_in[2];
    const float* Wk = (const float*)d_in[3];
    const float* bk = (const float*)d_in[4];
    const float* Wv = (const float*)d_in[5];
    const float* bv = (const float*)d_in[6];
    const float* Wo = (const float*)d_in[7];
    const float* bo = (const float*)d_in[8];
    float* out = (float*)d_out;

    const int T = 4096;          // B*S tokens
    const int H = 2048;          // hidden
    bf16_t* ws  = (bf16_t*)d_ws;
    bf16_t* xb  = ws;                         // T*H
    bf16_t* wqb = xb  + (size_t)T * H;        // H*H (Wq; Wk follows contiguously)
    bf16_t* wkb = wqb + (size_t)H * H;
    bf16_t* wvb = wkb + (size_t)H * H;
    bf16_t* wob = wvb + (size_t)H * H;
    bf16_t* QKb = wob + (size_t)H * H;        // T x 4096 (cols 0..2047=Q, 2048..4095=K)
    bf16_t* Vtb = QKb + (size_t)T * 2 * H;    // H x T (V transposed: feature-major)
    bf16_t* Ab  = Vtb + (size_t)H * T;        // T*H attention context
    size_t need = (size_t)(Ab + (size_t)T * H - ws) * sizeof(bf16_t);
    if (ws_size < need) return;

    cvt_f32_bf16<<<T * H / 2048, 256, 0, stream>>>(x, xb);
    cvt_f32_bf16<<<H * H / 2048, 256, 0, stream>>>(Wq, wqb);
    cvt_f32_bf16<<<H * H / 2048, 256, 0, stream>>>(Wk, wkb);
    cvt_f32_bf16<<<H * H / 2048, 256, 0, stream>>>(Wv, wvb);
    cvt_f32_bf16<<<H * H / 2048, 256, 0, stream>>>(Wo, wob);

    // merged Q|K projection: B = [Wq;Wk] (4096 x 2048), split col bias, ldc=4096
    dim3 gqk(T / 128, 4096 / 128);  // 1024 blocks
    gemm_bt<false, false><<<gqk, 256, 0, stream>>>(xb, wqb, bq, bk, H,
                                                   nullptr, QKb, T, 4096, H, 4096);
    // V^T = Wv * x^T : swap operands, bias per row (feature), ldc = T
    dim3 gv(H / 128, T / 128);
    gemm_bt<false, true><<<gv, 256, 0, stream>>>(wvb, xb, bv, nullptr, 0,
                                                 nullptr, Vtb, H, T, H, T);

    flash_attn<<<dim3(32, 16, 2), 128, 0, stream>>>(QKb, QKb + H, Vtb, Ab);

    dim3 go(T / 128, H / 128);
    gemm_bt<true, false><<<go, 256, 0, stream>>>(Ab, wob, bo, nullptr, H,
                                                 out, nullptr, T, H, H, H);
}